// Round 5
// baseline (1411.177 us; speedup 1.0000x reference)
//
#include <hip/hip_runtime.h>
#include <hip/hip_bf16.h>
#include <cfloat>
#include <type_traits>

// Problem constants
#define BB 8
#define TT 2048
#define CC 512
#define NNODE 1024

// ---------------------------------------------------------------------------
// Order-preserving f32 <-> u32 key
// ---------------------------------------------------------------------------
__device__ __forceinline__ unsigned fkey(float v) {
  unsigned u = __float_as_uint(v);
  return (u & 0x80000000u) ? ~u : (u | 0x80000000u);
}
__device__ __forceinline__ float fdec(unsigned k) {
  unsigned u = (k & 0x80000000u) ? (k & 0x7FFFFFFFu) : ~k;
  return __uint_as_float(u);
}

// ---------------------------------------------------------------------------
// Generic tiled GEMM: C[m,n] = alpha * sum_k A[m,k] * B(k,n) (+ bias)
//   TRANS_B=false : B is (K x N) row-major ; TRANS_B=true : B is (N x K)
//   BIAS_MODE: 0 none, 1 per-row (bias[m]), 2 per-col (bias[n])
//   OUT_BF16: write __hip_bfloat16 ; ACC64: accumulate in double
// 64x64 tile, BK=16, 256 threads, 4x4 microtile. Dims multiples of 64.
// ---------------------------------------------------------------------------
template <int BIAS_MODE, bool TRANS_B, bool OUT_BF16, bool ACC64>
__global__ __launch_bounds__(256) void gemm_kernel(
    const float* __restrict__ A, const float* __restrict__ Bm,
    void* __restrict__ Cp, const float* __restrict__ bias,
    int M, int N, int K, int lda, int ldb, int ldc,
    long long strideA, long long strideB, long long strideC, float alpha) {
  __shared__ float As[16][65];
  __shared__ float Bs[16][65];
  using AccT = typename std::conditional<ACC64, double, float>::type;

  const int b = blockIdx.z;
  A += (long long)b * strideA;
  Bm += (long long)b * strideB;

  const int m0 = blockIdx.y * 64;
  const int n0 = blockIdx.x * 64;
  const int tid = threadIdx.x;
  const int tx = tid & 15;
  const int ty = tid >> 4;

  AccT acc[4][4] = {};

  for (int k0 = 0; k0 < K; k0 += 16) {
#pragma unroll
    for (int i = 0; i < 4; ++i) {
      int idx = tid + i * 256;
      int am = idx >> 4, ak = idx & 15;
      As[ak][am] = A[(long long)(m0 + am) * lda + (k0 + ak)];
    }
    if (!TRANS_B) {
#pragma unroll
      for (int i = 0; i < 4; ++i) {
        int idx = tid + i * 256;
        int bn = idx & 63, bk = idx >> 6;
        Bs[bk][bn] = Bm[(long long)(k0 + bk) * ldb + (n0 + bn)];
      }
    } else {
#pragma unroll
      for (int i = 0; i < 4; ++i) {
        int idx = tid + i * 256;
        int bk = idx & 15, bn = idx >> 4;
        Bs[bk][bn] = Bm[(long long)(n0 + bn) * ldb + (k0 + bk)];
      }
    }
    __syncthreads();

#pragma unroll
    for (int k = 0; k < 16; ++k) {
      float a[4], bb[4];
#pragma unroll
      for (int i = 0; i < 4; ++i) a[i] = As[k][ty + i * 16];
#pragma unroll
      for (int j = 0; j < 4; ++j) bb[j] = Bs[k][tx + j * 16];
      if (ACC64) {
#pragma unroll
        for (int i = 0; i < 4; ++i)
#pragma unroll
          for (int j = 0; j < 4; ++j)
            acc[i][j] = (AccT)fma((double)a[i], (double)bb[j], (double)acc[i][j]);
      } else {
#pragma unroll
        for (int i = 0; i < 4; ++i)
#pragma unroll
          for (int j = 0; j < 4; ++j)
            acc[i][j] = (AccT)fmaf(a[i], bb[j], (float)acc[i][j]);
      }
    }
    __syncthreads();
  }

#pragma unroll
  for (int i = 0; i < 4; ++i) {
    int m = m0 + ty + i * 16;
#pragma unroll
    for (int j = 0; j < 4; ++j) {
      int n = n0 + tx + j * 16;
      float v = (float)(acc[i][j] * (AccT)alpha);
      if (BIAS_MODE == 1) v += bias[m];
      if (BIAS_MODE == 2) v += bias[n];
      long long off = strideC * b + (long long)m * ldc + n;
      if (OUT_BF16)
        ((__hip_bfloat16*)Cp)[off] = __float2bfloat16(v);
      else
        ((float*)Cp)[off] = v;
    }
  }
}

__global__ __launch_bounds__(256) void fill_zero(unsigned* __restrict__ p, long long n) {
  long long i = (long long)blockIdx.x * 256 + threadIdx.x;
  long long stride = (long long)gridDim.x * 256;
  for (; i < n; i += stride) p[i] = 0u;
}

// ---------------------------------------------------------------------------
// sim tile (f64 acc, no store) + per-token argmax over nodes via packed u64
// amaxIdx[b,t] = (fkey(sim_f32) << 32) | winning_node
// ---------------------------------------------------------------------------
__global__ __launch_bounds__(256) void sim_argmax_kernel(
    const float* __restrict__ q, const float* __restrict__ k,
    unsigned long long* __restrict__ amaxIdx) {
  __shared__ float As[16][65];
  __shared__ float Bs[16][65];
  __shared__ unsigned long long colmax[64];

  const int b = blockIdx.z;
  const float* A = q + (size_t)b * NNODE * CC;
  const float* Bm = k + (size_t)b * TT * CC;
  const int n0 = blockIdx.y * 64;
  const int t0 = blockIdx.x * 64;
  const int tid = threadIdx.x;
  const int tx = tid & 15;
  const int ty = tid >> 4;

  double acc[4][4] = {};

  for (int k0 = 0; k0 < CC; k0 += 16) {
#pragma unroll
    for (int i = 0; i < 4; ++i) {
      int idx = tid + i * 256;
      int am = idx >> 4, ak = idx & 15;
      As[ak][am] = A[(size_t)(n0 + am) * CC + (k0 + ak)];
    }
#pragma unroll
    for (int i = 0; i < 4; ++i) {
      int idx = tid + i * 256;
      int bk = idx & 15, bn = idx >> 4;
      Bs[bk][bn] = Bm[(size_t)(t0 + bn) * CC + (k0 + bk)];
    }
    __syncthreads();
#pragma unroll
    for (int kk = 0; kk < 16; ++kk) {
      float a[4], bb[4];
#pragma unroll
      for (int i = 0; i < 4; ++i) a[i] = As[kk][ty + i * 16];
#pragma unroll
      for (int j = 0; j < 4; ++j) bb[j] = Bs[kk][tx + j * 16];
#pragma unroll
      for (int i = 0; i < 4; ++i)
#pragma unroll
        for (int j = 0; j < 4; ++j)
          acc[i][j] = fma((double)a[i], (double)bb[j], acc[i][j]);
    }
    __syncthreads();
  }

  if (tid < 64) colmax[tid] = 0ULL;
  __syncthreads();

  const double scl = 0.04419417382415922;  // 512^-0.5
#pragma unroll
  for (int j = 0; j < 4; ++j) {
    float best = -FLT_MAX;
    int bestn = n0;
#pragma unroll
    for (int i = 0; i < 4; ++i) {
      float v = (float)(acc[i][j] * scl);
      if (v > best) { best = v; bestn = n0 + ty + i * 16; }
    }
    unsigned long long pk = ((unsigned long long)fkey(best) << 32) | (unsigned)bestn;
    atomicMax(&colmax[tx + j * 16], pk);
  }
  __syncthreads();
  if (tid < 64)
    atomicMax(&amaxIdx[(size_t)b * TT + t0 + tid], colmax[tid]);
}

__global__ __launch_bounds__(256) void node_max_kernel(
    const unsigned long long* __restrict__ amaxIdx, unsigned* __restrict__ Mpack) {
  int i = blockIdx.x * 256 + threadIdx.x;  // [0, B*T)
  unsigned long long pk = amaxIdx[i];
  int b = i >> 11;
  unsigned w = (unsigned)pk;
  atomicMax(&Mpack[b * NNODE + w], (unsigned)(pk >> 32));
}

__global__ __launch_bounds__(256) void node_denom_kernel(
    const unsigned long long* __restrict__ amaxIdx, const unsigned* __restrict__ Mpack,
    float* __restrict__ D, float* __restrict__ att_val) {
  int i = blockIdx.x * 256 + threadIdx.x;
  unsigned long long pk = amaxIdx[i];
  int b = i >> 11;
  unsigned w = (unsigned)pk;
  float amaxf = fdec((unsigned)(pk >> 32));
  float Mf = fdec(Mpack[b * NNODE + w]);
  float e = expf(amaxf - Mf);
  att_val[i] = e;
  atomicAdd(&D[b * NNODE + w], e);
}

// att finalize + scatter FLOAT32 att into d_out (att region pre-zeroed)
__global__ __launch_bounds__(256) void att_write_kernel(
    const unsigned long long* __restrict__ amaxIdx, const float* __restrict__ D,
    float* __restrict__ att_val, float* __restrict__ att_out) {
  int i = blockIdx.x * 256 + threadIdx.x;
  unsigned long long pk = amaxIdx[i];
  int b = i >> 11;
  int t = i & (TT - 1);
  unsigned w = (unsigned)pk;
  float a = att_val[i] / D[b * NNODE + w];
  att_val[i] = a;
  att_out[((size_t)b * NNODE + w) * TT + t] = a;
}

__global__ __launch_bounds__(256) void pv_scatter_kernel(
    const unsigned long long* __restrict__ amaxIdx, const float* __restrict__ att_val,
    const __hip_bfloat16* __restrict__ v, float* __restrict__ out0) {
  int bt = blockIdx.x;  // [0, B*T)
  int b = bt >> 11;
  float a = att_val[bt];
  unsigned w = (unsigned)amaxIdx[bt];
  const __hip_bfloat16* vr = v + (size_t)bt * CC;
  float* orow = out0 + ((size_t)b * NNODE + w) * CC;
  for (int c = threadIdx.x; c < CC; c += 256)
    atomicAdd(&orow[c], a * __bfloat162float(vr[c]));
}

extern "C" void kernel_launch(void* const* d_in, const int* in_sizes, int n_in,
                              void* d_out, int out_size, void* d_ws, size_t ws_size,
                              hipStream_t stream) {
  const float* x = (const float*)d_in[0];     // [B,T,C]  f32
  const float* Wq = (const float*)d_in[1];    // [N,T]
  const float* bq = (const float*)d_in[2];    // [N]
  const float* Wk = (const float*)d_in[3];    // [C,C]
  const float* Wv = (const float*)d_in[4];    // [C,C]
  const float* Wout = (const float*)d_in[5];  // [C,C]
  const float* bout = (const float*)d_in[6];  // [C]

  // OUTPUTS ARE FLOAT32 (reference output dtype).
  float* out = (float*)d_out;                       // [B,N,C] f32
  float* att_out = out + (size_t)BB * NNODE * CC;   // [B,N,T] f32

  // Workspace layout: q(16MB f32) | k(32MB f32) | v(16MB bf16) | small. ~64.3MB
  float* ws = (float*)d_ws;
  float* q = ws;                                // B*N*C f32 (reused as out0)
  float* kbuf = q + (size_t)BB * NNODE * CC;    // B*T*C f32
  __hip_bfloat16* vbuf = (__hip_bfloat16*)(kbuf + (size_t)BB * TT * CC);  // B*T*C bf16
  unsigned long long* amaxIdx =
      (unsigned long long*)((unsigned*)vbuf + (size_t)BB * TT * CC / 2);  // B*T u64
  unsigned* Mpack = (unsigned*)(amaxIdx + (size_t)BB * TT);               // B*N u32
  float* D = (float*)(Mpack + (size_t)BB * NNODE);                        // B*N f32
  float* att_val = D + (size_t)BB * NNODE;                                // B*T f32
  float* out0 = q;

  dim3 blk(256);

  // Z1: zero amaxIdx|Mpack|D (contiguous small state)
  fill_zero<<<dim3(64), blk, 0, stream>>>(
      (unsigned*)amaxIdx, (long long)BB * TT * 2 + (long long)BB * NNODE * 2);
  // Z1b: zero att region of d_out (B*N*T f32 words)
  fill_zero<<<dim3(4096), blk, 0, stream>>>(
      (unsigned*)att_out, (long long)BB * NNODE * TT);

  // q[b,n,c] = sum_t Wq[n,t] x[b,t,c] + bq[n]  (f64 acc, decision path)
  gemm_kernel<1, false, false, true><<<dim3(CC / 64, NNODE / 64, BB), blk, 0, stream>>>(
      Wq, x, q, bq, NNODE, CC, TT, TT, CC, CC,
      0LL, (long long)TT * CC, (long long)NNODE * CC, 1.0f);

  // k[b,t,d] = sum_c x[b,t,c] Wk[d,c]  (f64 acc, decision path)
  gemm_kernel<0, true, false, true><<<dim3(CC / 64, TT / 64, BB), blk, 0, stream>>>(
      x, Wk, kbuf, nullptr, TT, CC, CC, CC, CC, CC,
      (long long)TT * CC, 0LL, (long long)TT * CC, 1.0f);

  // v[b,t,d] (bf16 store, value path)
  gemm_kernel<0, true, true, false><<<dim3(CC / 64, TT / 64, BB), blk, 0, stream>>>(
      x, Wv, vbuf, nullptr, TT, CC, CC, CC, CC, CC,
      (long long)TT * CC, 0LL, (long long)TT * CC, 1.0f);

  // fused sim + per-token argmax over nodes (no sim materialization)
  sim_argmax_kernel<<<dim3(TT / 64, NNODE / 64, BB), blk, 0, stream>>>(q, kbuf, amaxIdx);

  // zero out0 (aliases q; q dead after sim_argmax)
  fill_zero<<<dim3(2048), blk, 0, stream>>>((unsigned*)out0, (long long)BB * NNODE * CC);

  node_max_kernel<<<dim3(BB * TT / 256), blk, 0, stream>>>(amaxIdx, Mpack);
  node_denom_kernel<<<dim3(BB * TT / 256), blk, 0, stream>>>(amaxIdx, Mpack, D, att_val);
  att_write_kernel<<<dim3(BB * TT / 256), blk, 0, stream>>>(amaxIdx, D, att_val, att_out);

  // sparse PV scatter: out0[b,w,c] += att * v[b,t,c]
  pv_scatter_kernel<<<dim3(BB * TT), blk, 0, stream>>>(amaxIdx, att_val, vbuf, out0);

  // out[b,n,d] = sum_c out0[b,n,c] Wout[d,c] + bout[d]  (FLOAT32 store)
  gemm_kernel<2, true, false, false><<<dim3(CC / 64, NNODE / 64, BB), blk, 0, stream>>>(
      out0, Wout, out, bout, NNODE, CC, CC, CC, CC, CC,
      (long long)NNODE * CC, 0LL, (long long)NNODE * CC, 1.0f);
}